// Round 1
// baseline (807.715 us; speedup 1.0000x reference)
//
#include <hip/hip_runtime.h>

// ---------------------------------------------------------------------------
// GraphSAGE 2-layer (mean aggr), N=100000, E=1600000, 128 -> 128(relu) -> 64
//
// Strategy: project-then-aggregate (linearity of mean):
//   h   = relu( agg(x@W1l^T)/deg + b1 + x@W1r^T )
//   out =       agg(h@W2l^T)/deg + b2 + h@W2r^T
// CSR built on-device every launch (int atomics only; no float atomics).
// ---------------------------------------------------------------------------

namespace {
constexpr int NN = 100000;
constexpr int NE = 1600000;

// workspace layout, in 4-byte words (all regions 256B-aligned)
constexpr size_t W_CNT = 0;                               // int[NN]
constexpr size_t W_CUR = 100032;                          // int[NN]
constexpr size_t W_OFF = 200064;                          // int[NN+1]
constexpr size_t W_CSR = 300160;                          // int[NE]
constexpr size_t W_XLR = 1900160;                         // float[NN*256]; reused as hlr
constexpr size_t W_H   = W_XLR + (size_t)NN * 256;        // float[NN*128]
// total = 40,300,160 words = 161.2 MB
}

// ---------------- CSR build ----------------

__global__ void count_k(const int* __restrict__ dst, int* __restrict__ cnt) {
  int e = blockIdx.x * blockDim.x + threadIdx.x;
  if (e < NE) atomicAdd(&cnt[dst[e]], 1);
}

__global__ void scan_k(const int* __restrict__ cnt, int* __restrict__ off) {
  __shared__ int part[1024];
  int t = threadIdx.x;
  const int chunk = (NN + 1023) / 1024;   // 98
  int lo = t * chunk, hi = min(lo + chunk, NN);
  int s = 0;
  for (int i = lo; i < hi; ++i) s += cnt[i];
  part[t] = s;
  __syncthreads();
  // Hillis-Steele inclusive scan over 1024 partials
  for (int d = 1; d < 1024; d <<= 1) {
    int v = (t >= d) ? part[t - d] : 0;
    __syncthreads();
    part[t] += v;
    __syncthreads();
  }
  int run = (t == 0) ? 0 : part[t - 1];
  for (int i = lo; i < hi; ++i) { off[i] = run; run += cnt[i]; }
  if (t == 1023) off[NN] = part[1023];
}

__global__ void fill_k(const int* __restrict__ src, const int* __restrict__ dst,
                       const int* __restrict__ off, int* __restrict__ cur,
                       int* __restrict__ csr) {
  int e = blockIdx.x * blockDim.x + threadIdx.x;
  if (e >= NE) return;
  int d = dst[e];
  int p = atomicAdd(&cur[d], 1);
  csr[off[d] + p] = src[e];
}

// ---------------- fp32 GEMM: C[m, n0+n] = sum_k A[m,k] * W[n,k] ----------------
// W rows come from two stacked matrices: row R < split -> Wlo[R], else Whi[R-split].
// Tile 128x128, K=128 (full). 256 threads, 8x8 micro-tile per thread.
// LDS 128 KiB, XOR-swizzled 16B granules to kill bank conflicts.

__launch_bounds__(256, 1)
__global__ void gemm_xwt_k(const float* __restrict__ A, int M,
                           const float* __restrict__ Wlo, const float* __restrict__ Whi,
                           int split, int Nw,
                           float* __restrict__ C, int ldC) {
  __shared__ float As[128 * 128];   // [m][k], 64 KiB
  __shared__ float Bs[128 * 128];   // [n][k], 64 KiB
  const int t  = threadIdx.x;
  const int m0 = blockIdx.x * 128;
  const int n0 = blockIdx.y * 128;

  // stage A tile (zero-fill rows >= M)
  #pragma unroll
  for (int ii = 0; ii < 16; ++ii) {
    int G = t + 256 * ii;          // 16B-granule id, 0..4095 (32 granules/row)
    int r = G >> 5, g = G & 31;
    int m = m0 + r;
    float4 v = make_float4(0.f, 0.f, 0.f, 0.f);
    if (m < M) v = *(const float4*)(A + (size_t)m * 128 + g * 4);
    int gs = g ^ (r & 7);
    *(float4*)(As + r * 128 + gs * 4) = v;
  }
  // stage B tile from stacked weights
  #pragma unroll
  for (int ii = 0; ii < 16; ++ii) {
    int G = t + 256 * ii;
    int r = G >> 5, g = G & 31;
    int R = n0 + r;
    float4 v = make_float4(0.f, 0.f, 0.f, 0.f);
    if (R < Nw) {
      const float* Wrow = (R < split) ? (Wlo + (size_t)R * 128)
                                      : (Whi + (size_t)(R - split) * 128);
      v = *(const float4*)(Wrow + g * 4);
    }
    int gs = g ^ (r & 7);
    *(float4*)(Bs + r * 128 + gs * 4) = v;
  }
  __syncthreads();

  const int tn = t & 15, tm = t >> 4;   // 16x16 thread grid
  const int aslot = tm & 7, bslot = tn & 7;
  float acc[8][8];
  #pragma unroll
  for (int i = 0; i < 8; ++i)
    #pragma unroll
    for (int j = 0; j < 8; ++j) acc[i][j] = 0.f;

  for (int g = 0; g < 32; ++g) {        // 4 k per iter
    float4 av[8], bv[8];
    #pragma unroll
    for (int i = 0; i < 8; ++i)
      av[i] = *(const float4*)(As + (tm + 16 * i) * 128 + ((g ^ aslot) << 2));
    #pragma unroll
    for (int j = 0; j < 8; ++j)
      bv[j] = *(const float4*)(Bs + (tn + 16 * j) * 128 + ((g ^ bslot) << 2));
    #pragma unroll
    for (int i = 0; i < 8; ++i)
      #pragma unroll
      for (int j = 0; j < 8; ++j) {
        acc[i][j] = fmaf(av[i].x, bv[j].x, acc[i][j]);
        acc[i][j] = fmaf(av[i].y, bv[j].y, acc[i][j]);
        acc[i][j] = fmaf(av[i].z, bv[j].z, acc[i][j]);
        acc[i][j] = fmaf(av[i].w, bv[j].w, acc[i][j]);
      }
  }

  #pragma unroll
  for (int i = 0; i < 8; ++i) {
    int m = m0 + tm + 16 * i;
    if (m >= M) continue;
    #pragma unroll
    for (int j = 0; j < 8; ++j) {
      int n = n0 + tn + 16 * j;
      if (n < Nw) C[(size_t)m * ldC + n] = acc[i][j];
    }
  }
}

// ---------------- layer-1 aggregate + bias + self + relu ----------------
// one wave per node; lane owns 2 cols (float2). xlr: [NN][256], xl=cols 0..127,
// xr=cols 128..255. Writes h [NN][128].

__launch_bounds__(256)
__global__ void agg1_k(const float* __restrict__ xlr, const int* __restrict__ off,
                       const int* __restrict__ csr, const float* __restrict__ b1,
                       float* __restrict__ h) {
  int wid  = (blockIdx.x * blockDim.x + threadIdx.x) >> 6;
  int lane = threadIdx.x & 63;
  if (wid >= NN) return;
  int s0 = off[wid], s1 = off[wid + 1];
  int c = lane * 2;
  float ax = 0.f, ay = 0.f;
  int e = s0;
  for (; e + 1 < s1; e += 2) {       // unroll 2: two gathers in flight
    int j0 = csr[e], j1 = csr[e + 1];
    float2 v0 = *(const float2*)(xlr + (size_t)j0 * 256 + c);
    float2 v1 = *(const float2*)(xlr + (size_t)j1 * 256 + c);
    ax += v0.x + v1.x; ay += v0.y + v1.y;
  }
  if (e < s1) {
    int j0 = csr[e];
    float2 v0 = *(const float2*)(xlr + (size_t)j0 * 256 + c);
    ax += v0.x; ay += v0.y;
  }
  float inv = 1.f / fmaxf((float)(s1 - s0), 1.f);
  float2 r  = *(const float2*)(xlr + (size_t)wid * 256 + 128 + c);
  float2 bb = *(const float2*)(b1 + c);
  float2 hv;
  hv.x = fmaxf(fmaf(ax, inv, bb.x + r.x), 0.f);
  hv.y = fmaxf(fmaf(ay, inv, bb.y + r.y), 0.f);
  *(float2*)(h + (size_t)wid * 128 + c) = hv;
}

// ---------------- layer-2 aggregate + bias + self -> out ----------------
// one wave per node; lane owns 1 col. hlr: [NN][128], hl=cols 0..63, hr=64..127.

__launch_bounds__(256)
__global__ void agg2_k(const float* __restrict__ hlr, const int* __restrict__ off,
                       const int* __restrict__ csr, const float* __restrict__ b2,
                       float* __restrict__ out) {
  int wid  = (blockIdx.x * blockDim.x + threadIdx.x) >> 6;
  int lane = threadIdx.x & 63;
  if (wid >= NN) return;
  int s0 = off[wid], s1 = off[wid + 1];
  float a = 0.f;
  int e = s0;
  for (; e + 1 < s1; e += 2) {
    int j0 = csr[e], j1 = csr[e + 1];
    float v0 = hlr[(size_t)j0 * 128 + lane];
    float v1 = hlr[(size_t)j1 * 128 + lane];
    a += v0 + v1;
  }
  if (e < s1) a += hlr[(size_t)csr[e] * 128 + lane];
  float inv = 1.f / fmaxf((float)(s1 - s0), 1.f);
  float r   = hlr[(size_t)wid * 128 + 64 + lane];
  out[(size_t)wid * 64 + lane] = fmaf(a, inv, b2[lane] + r);
}

// ---------------- launch ----------------

extern "C" void kernel_launch(void* const* d_in, const int* in_sizes, int n_in,
                              void* d_out, int out_size, void* d_ws, size_t ws_size,
                              hipStream_t stream) {
  const float* x    = (const float*)d_in[0];
  const int*   ei   = (const int*)d_in[1];     // [2][NE] int32
  const float* w1l  = (const float*)d_in[2];
  const float* b1   = (const float*)d_in[3];
  const float* w1r  = (const float*)d_in[4];
  const float* w2l  = (const float*)d_in[5];
  const float* b2   = (const float*)d_in[6];
  const float* w2r  = (const float*)d_in[7];
  float* out = (float*)d_out;

  const int* src = ei;
  const int* dst = ei + NE;

  int*   cnt = (int*)d_ws + W_CNT;
  int*   cur = (int*)d_ws + W_CUR;
  int*   off = (int*)d_ws + W_OFF;
  int*   csr = (int*)d_ws + W_CSR;
  float* xlr = (float*)d_ws + W_XLR;   // [NN][256]
  float* hlr = (float*)d_ws + W_XLR;   // reuse after xlr is dead
  float* h   = (float*)d_ws + W_H;     // [NN][128]

  // zero cnt + cur (contiguous)
  hipMemsetAsync((int*)d_ws + W_CNT, 0, (W_OFF - W_CNT) * 4, stream);

  const int eb = (NE + 255) / 256;
  count_k<<<eb, 256, 0, stream>>>(dst, cnt);
  scan_k<<<1, 1024, 0, stream>>>(cnt, off);
  fill_k<<<eb, 256, 0, stream>>>(src, dst, off, cur, csr);

  // GEMM1: xlr = x @ [W1l | W1r]^T   -> [NN][256]
  gemm_xwt_k<<<dim3((NN + 127) / 128, 2), 256, 0, stream>>>(
      x, NN, w1l, w1r, /*split=*/128, /*Nw=*/256, xlr, /*ldC=*/256);

  // agg1: h = relu(mean(xl) + b1 + xr)
  agg1_k<<<(NN * 64 + 255) / 256, 256, 0, stream>>>(xlr, off, csr, b1, h);

  // GEMM2: hlr = h @ [W2l | W2r]^T   -> [NN][128]
  gemm_xwt_k<<<dim3((NN + 127) / 128, 1), 256, 0, stream>>>(
      h, NN, w2l, w2r, /*split=*/64, /*Nw=*/128, hlr, /*ldC=*/128);

  // agg2: out = mean(hl) + b2 + hr
  agg2_k<<<(NN * 64 + 255) / 256, 256, 0, stream>>>(hlr, off, csr, b2, out);
}

// Round 2
// 497.529 us; speedup vs baseline: 1.6235x; 1.6235x over previous
//
#include <hip/hip_runtime.h>

// ---------------------------------------------------------------------------
// GraphSAGE 2-layer (mean aggr), N=100000, E=1600000, 128 -> 128(relu) -> 64
// Project-then-aggregate; bf16 MFMA GEMMs; bf16 intermediate features to
// halve gather traffic; CSR built on-device (int atomics only).
// ---------------------------------------------------------------------------

namespace {
constexpr int NN = 100000;
constexpr int NE = 1600000;

// workspace layout in 4-byte words (all regions 16B-aligned)
constexpr size_t W_CNT = 0;          // int[NN]
constexpr size_t W_CUR = 100032;     // int[NN]
constexpr size_t W_OFF = 200064;     // int[NN+1]
constexpr size_t W_CSR = 300160;     // int[NE]
constexpr size_t W_B1  = 1900160;    // ushort[8*8*64*8]  = 64 KB packed W1
constexpr size_t W_B2  = 1916544;    // ushort[4*8*64*8]  = 32 KB packed W2
constexpr size_t W_XLR = 1924736;    // bf16 [NN][256]
constexpr size_t W_H   = 14724736;   // bf16 [NN][128]
constexpr size_t W_HLR = 21124736;   // bf16 [NN][128]
// end = 27,524,736 words = 110 MB (round-1 used 161 MB OK)
}

using short8  = __attribute__((ext_vector_type(8)))  short;
using f32x16  = __attribute__((ext_vector_type(16))) float;

__device__ inline unsigned short f2b(float f) {   // fp32 -> bf16 RNE
  unsigned u = __builtin_bit_cast(unsigned, f);
  u = (u + 0x7fffu + ((u >> 16) & 1u)) >> 16;
  return (unsigned short)u;
}
__device__ inline float b2f_lo(unsigned u) { return __builtin_bit_cast(float, u << 16); }
__device__ inline float b2f_hi(unsigned u) { return __builtin_bit_cast(float, u & 0xffff0000u); }
__device__ inline float b2f(unsigned short s) { return __builtin_bit_cast(float, ((unsigned)s) << 16); }

// ---------------- CSR build ----------------

__global__ void count_k(const int* __restrict__ dst, int* __restrict__ cnt) {
  int e = blockIdx.x * blockDim.x + threadIdx.x;
  if (e < NE) atomicAdd(&cnt[dst[e]], 1);
}

__global__ void scan_k(const int* __restrict__ cnt, int* __restrict__ off) {
  __shared__ int part[1024];
  int t = threadIdx.x;
  const int chunk = (NN + 1023) / 1024;   // 98
  int lo = t * chunk, hi = min(lo + chunk, NN);
  int s = 0;
  for (int i = lo; i < hi; ++i) s += cnt[i];
  part[t] = s;
  __syncthreads();
  for (int d = 1; d < 1024; d <<= 1) {
    int v = (t >= d) ? part[t - d] : 0;
    __syncthreads();
    part[t] += v;
    __syncthreads();
  }
  int run = (t == 0) ? 0 : part[t - 1];
  for (int i = lo; i < hi; ++i) { off[i] = run; run += cnt[i]; }
  if (t == 1023) off[NN] = part[1023];
}

__global__ void fill_k(const int* __restrict__ src, const int* __restrict__ dst,
                       const int* __restrict__ off, int* __restrict__ cur,
                       int* __restrict__ csr) {
  int e = blockIdx.x * blockDim.x + threadIdx.x;
  if (e >= NE) return;
  int d = dst[e];
  int p = atomicAdd(&cur[d], 1);
  csr[off[d] + p] = src[e];
}

// ---------------- pack weights into 32x32x16 MFMA B-fragment order ---------
// Bpack[nf][kk][lane][j]: n = nf*32 + (lane&31);
//   j=0..3 -> k = kk*16 +     (lane>>5)*4 + j
//   j=4..7 -> k = kk*16 + 8 + (lane>>5)*4 + (j-4)
// entries 0..4095 -> Bpack1 (N=256: W1l rows 0-127, W1r rows 128-255)
// entries 4096..6143 -> Bpack2 (N=128: W2l rows 0-63, W2r rows 64-127)

__global__ void prep_b_k(const float* __restrict__ w1l, const float* __restrict__ w1r,
                         const float* __restrict__ w2l, const float* __restrict__ w2r,
                         unsigned short* __restrict__ b1p, unsigned short* __restrict__ b2p) {
  int e = blockIdx.x * blockDim.x + threadIdx.x;
  if (e >= 6144) return;
  bool g2 = e >= 4096;
  int le = g2 ? e - 4096 : e;
  int nf = le >> 9, kk = (le >> 6) & 7, l = le & 63;
  int n = nf * 32 + (l & 31), half = l >> 5;
  const float* Wlo = g2 ? w2l : w1l;
  const float* Whi = g2 ? w2r : w1r;
  int split = g2 ? 64 : 128;
  unsigned short o[8];
  #pragma unroll
  for (int j = 0; j < 8; ++j) {
    int k = kk * 16 + ((j >= 4) ? 8 : 0) + half * 4 + (j & 3);
    float v = (n < split) ? Wlo[(size_t)n * 128 + k] : Whi[(size_t)(n - split) * 128 + k];
    o[j] = f2b(v);
  }
  unsigned short* dstp = (g2 ? b2p : b1p) + (size_t)le * 8;
  *(short8*)dstp = __builtin_bit_cast(short8, *(const ulonglong2*)o);
}

// ---------------- MFMA GEMM: C[m,n] = sum_k A[m,k]*W[n,k], K=128 ----------
// BM=128, 512 threads = 8 waves (4 row-waves x 2 col-waves).
// A staged in LDS (bf16, XOR-swizzled 16B granules); B-frags streamed from
// packed global (coalesced 1KB/instr, L2-hot).

template<int NCOLS, bool AFP32>
__global__ __launch_bounds__(512, 2) void gemm_k(const void* __restrict__ Aptr, int M,
                                                 const unsigned short* __restrict__ Bpack,
                                                 unsigned short* __restrict__ C) {
  constexpr int NF = NCOLS / 64;          // n-frags per wave
  __shared__ unsigned short As[128 * 128];
  const int t  = threadIdx.x;
  const int m0 = blockIdx.x * 128;

  // stage A: 2048 16B-granules, 4 per thread; fp32->bf16 convert if needed
  #pragma unroll
  for (int i = 0; i < 4; ++i) {
    int G = t + 512 * i;
    int r = G >> 4, g = G & 15;
    int m = m0 + r;
    short8 v = {0, 0, 0, 0, 0, 0, 0, 0};
    if (AFP32) {
      if (m < M) {
        const float* p = (const float*)Aptr + (size_t)m * 128 + g * 8;
        float4 a = *(const float4*)p;
        float4 b = *(const float4*)(p + 4);
        v[0] = (short)f2b(a.x); v[1] = (short)f2b(a.y);
        v[2] = (short)f2b(a.z); v[3] = (short)f2b(a.w);
        v[4] = (short)f2b(b.x); v[5] = (short)f2b(b.y);
        v[6] = (short)f2b(b.z); v[7] = (short)f2b(b.w);
      }
    } else {
      if (m < M) v = *(const short8*)((const unsigned short*)Aptr + (size_t)m * 128 + g * 8);
    }
    *(short8*)(As + r * 128 + ((g ^ (r & 15)) << 3)) = v;
  }
  __syncthreads();

  const int wid = t >> 6, lane = t & 63;
  const int mw = wid >> 1, nw = wid & 1;
  const int m = mw * 32 + (lane & 31), half = lane >> 5;

  // A-fragments for this wave's 32 rows, all K (8 frags of K=16)
  short8 af[8];
  #pragma unroll
  for (int kk = 0; kk < 8; ++kk) {
    const unsigned* p0 = (const unsigned*)(As + m * 128 + (((2 * kk)     ^ (m & 15)) << 3) + half * 4);
    const unsigned* p1 = (const unsigned*)(As + m * 128 + (((2 * kk + 1) ^ (m & 15)) << 3) + half * 4);
    uint4 comb = make_uint4(p0[0], p0[1], p1[0], p1[1]);
    af[kk] = __builtin_bit_cast(short8, comb);
  }

  #pragma unroll
  for (int nf = 0; nf < NF; ++nf) {
    const int nfg = nw * NF + nf;
    f32x16 acc;
    #pragma unroll
    for (int i = 0; i < 16; ++i) acc[i] = 0.f;
    #pragma unroll
    for (int kk = 0; kk < 8; ++kk) {
      short8 bf = *(const short8*)(Bpack + ((size_t)((nfg * 8 + kk) * 64 + lane)) * 8);
      acc = __builtin_amdgcn_mfma_f32_32x32x16_bf16(af[kk], bf, acc, 0, 0, 0);
    }
    const int col = nfg * 32 + (lane & 31);
    #pragma unroll
    for (int q = 0; q < 4; ++q)
      #pragma unroll
      for (int rr = 0; rr < 4; ++rr) {
        int row = rr + 8 * q + 4 * half;
        int mo  = m0 + mw * 32 + row;
        if (mo < M) C[(size_t)mo * NCOLS + col] = f2b(acc[q * 4 + rr]);
      }
  }
}

// ---------------- layer-1 aggregate + bias + self + relu (bf16 in/out) -----
// wave per node; lane owns cols 2l,2l+1 of the 128-wide xl part.

__global__ __launch_bounds__(256) void agg1_k(const unsigned short* __restrict__ xlr,
                                              const int* __restrict__ off,
                                              const int* __restrict__ csr,
                                              const float* __restrict__ b1,
                                              unsigned short* __restrict__ h) {
  int wid  = (blockIdx.x * blockDim.x + threadIdx.x) >> 6;
  int lane = threadIdx.x & 63;
  if (wid >= NN) return;
  int s0 = off[wid], s1 = off[wid + 1];
  float ax = 0.f, ay = 0.f;
  int e = s0;
  for (; e + 3 < s1; e += 4) {
    int j0 = csr[e], j1 = csr[e + 1], j2 = csr[e + 2], j3 = csr[e + 3];
    unsigned u0 = *(const unsigned*)(xlr + (size_t)j0 * 256 + 2 * lane);
    unsigned u1 = *(const unsigned*)(xlr + (size_t)j1 * 256 + 2 * lane);
    unsigned u2 = *(const unsigned*)(xlr + (size_t)j2 * 256 + 2 * lane);
    unsigned u3 = *(const unsigned*)(xlr + (size_t)j3 * 256 + 2 * lane);
    ax += (b2f_lo(u0) + b2f_lo(u1)) + (b2f_lo(u2) + b2f_lo(u3));
    ay += (b2f_hi(u0) + b2f_hi(u1)) + (b2f_hi(u2) + b2f_hi(u3));
  }
  for (; e < s1; ++e) {
    unsigned u = *(const unsigned*)(xlr + (size_t)csr[e] * 256 + 2 * lane);
    ax += b2f_lo(u); ay += b2f_hi(u);
  }
  float inv = 1.f / fmaxf((float)(s1 - s0), 1.f);
  unsigned su = *(const unsigned*)(xlr + (size_t)wid * 256 + 128 + 2 * lane);
  float2 bb = *(const float2*)(b1 + 2 * lane);
  float h0 = fmaxf(fmaf(ax, inv, bb.x + b2f_lo(su)), 0.f);
  float h1 = fmaxf(fmaf(ay, inv, bb.y + b2f_hi(su)), 0.f);
  unsigned packed = (unsigned)f2b(h0) | ((unsigned)f2b(h1) << 16);
  *(unsigned*)(h + (size_t)wid * 128 + 2 * lane) = packed;
}

// ---------------- layer-2 aggregate + bias + self -> out (fp32) ------------
// wave per node; lane owns 1 of 64 output cols.

__global__ __launch_bounds__(256) void agg2_k(const unsigned short* __restrict__ hlr,
                                              const int* __restrict__ off,
                                              const int* __restrict__ csr,
                                              const float* __restrict__ b2,
                                              float* __restrict__ out) {
  int wid  = (blockIdx.x * blockDim.x + threadIdx.x) >> 6;
  int lane = threadIdx.x & 63;
  if (wid >= NN) return;
  int s0 = off[wid], s1 = off[wid + 1];
  float a = 0.f;
  int e = s0;
  for (; e + 3 < s1; e += 4) {
    int j0 = csr[e], j1 = csr[e + 1], j2 = csr[e + 2], j3 = csr[e + 3];
    float v0 = b2f(hlr[(size_t)j0 * 128 + lane]);
    float v1 = b2f(hlr[(size_t)j1 * 128 + lane]);
    float v2 = b2f(hlr[(size_t)j2 * 128 + lane]);
    float v3 = b2f(hlr[(size_t)j3 * 128 + lane]);
    a += (v0 + v1) + (v2 + v3);
  }
  for (; e < s1; ++e) a += b2f(hlr[(size_t)csr[e] * 128 + lane]);
  float inv = 1.f / fmaxf((float)(s1 - s0), 1.f);
  float r   = b2f(hlr[(size_t)wid * 128 + 64 + lane]);
  out[(size_t)wid * 64 + lane] = fmaf(a, inv, b2[lane] + r);
}

// ---------------- launch ----------------

extern "C" void kernel_launch(void* const* d_in, const int* in_sizes, int n_in,
                              void* d_out, int out_size, void* d_ws, size_t ws_size,
                              hipStream_t stream) {
  const float* x   = (const float*)d_in[0];
  const int*   ei  = (const int*)d_in[1];   // harness delivers int32
  const float* w1l = (const float*)d_in[2];
  const float* b1  = (const float*)d_in[3];
  const float* w1r = (const float*)d_in[4];
  const float* w2l = (const float*)d_in[5];
  const float* b2  = (const float*)d_in[6];
  const float* w2r = (const float*)d_in[7];
  float* out = (float*)d_out;

  const int* src = ei;
  const int* dst = ei + NE;

  int* cnt = (int*)d_ws + W_CNT;
  int* cur = (int*)d_ws + W_CUR;
  int* off = (int*)d_ws + W_OFF;
  int* csr = (int*)d_ws + W_CSR;
  unsigned short* b1p = (unsigned short*)((int*)d_ws + W_B1);
  unsigned short* b2p = (unsigned short*)((int*)d_ws + W_B2);
  unsigned short* xlr = (unsigned short*)((int*)d_ws + W_XLR);  // [NN][256]
  unsigned short* h   = (unsigned short*)((int*)d_ws + W_H);    // [NN][128]
  unsigned short* hlr = (unsigned short*)((int*)d_ws + W_HLR);  // [NN][128]

  hipMemsetAsync((int*)d_ws + W_CNT, 0, (W_OFF - W_CNT) * 4, stream);

  const int eb = (NE + 255) / 256;
  count_k<<<eb, 256, 0, stream>>>(dst, cnt);
  scan_k<<<1, 1024, 0, stream>>>(cnt, off);
  fill_k<<<eb, 256, 0, stream>>>(src, dst, off, cur, csr);
  prep_b_k<<<24, 256, 0, stream>>>(w1l, w1r, w2l, w2r, b1p, b2p);

  const int gb = (NN + 127) / 128;   // 782

  // GEMM1: xlr = bf16( x @ [W1l|W1r]^T )  [NN][256]
  gemm_k<256, true><<<gb, 512, 0, stream>>>((const void*)x, NN, b1p, xlr);

  // agg1: h = bf16( relu(mean(xl) + b1 + xr) )  [NN][128]
  agg1_k<<<(NN * 64 + 255) / 256, 256, 0, stream>>>(xlr, off, csr, b1, h);

  // GEMM2: hlr = bf16( h @ [W2l|W2r]^T )  [NN][128]
  gemm_k<128, false><<<gb, 512, 0, stream>>>((const void*)h, NN, b2p, hlr);

  // agg2: out = mean(hl) + b2 + hr  (fp32)
  agg2_k<<<(NN * 64 + 255) / 256, 256, 0, stream>>>(hlr, off, csr, b2, out);
}

// Round 3
// 358.443 us; speedup vs baseline: 2.2534x; 1.3880x over previous
//
#include <hip/hip_runtime.h>

// ---------------------------------------------------------------------------
// GraphSAGE 2-layer (mean aggr), N=100000, E=1600000, 128 -> 128(relu) -> 64
// Project-then-aggregate; bf16 MFMA GEMMs; bf16 intermediate features;
// CSR built on-device with a 3-pass device-wide scan (int atomics only).
// ---------------------------------------------------------------------------

namespace {
constexpr int NN = 100000;
constexpr int NE = 1600000;
constexpr int NPAD = 100352;          // 98 * 1024, scan coverage (zero-padded)

// workspace layout in 4-byte words (all regions 16B-aligned)
constexpr size_t W_CNT  = 0;          // int[NPAD]
constexpr size_t W_CUR  = 100352;     // int[100032]
constexpr size_t W_BSUM = 200384;     // int[128]
constexpr size_t W_OFF  = 200512;     // int[100416] (off[0..NPAD] fits)
constexpr size_t W_CSR  = 300928;     // int[NE]
constexpr size_t W_B1   = 1900928;    // ushort[8*8*64*8]  = 64 KB packed W1
constexpr size_t W_B2   = 1917312;    // ushort[4*8*64*8]  = 32 KB packed W2
constexpr size_t W_XLR  = 1925504;    // bf16 [NN][256]
constexpr size_t W_H    = 14725504;   // bf16 [NN][128]
constexpr size_t W_HLR  = 21125504;   // bf16 [NN][128]
// end = 27,525,504 words = 110.1 MB
}

using short8  = __attribute__((ext_vector_type(8)))  short;
using f32x16  = __attribute__((ext_vector_type(16))) float;

__device__ inline unsigned short f2b(float f) {   // fp32 -> bf16 RNE
  unsigned u = __builtin_bit_cast(unsigned, f);
  u = (u + 0x7fffu + ((u >> 16) & 1u)) >> 16;
  return (unsigned short)u;
}
__device__ inline float b2f_lo(unsigned u) { return __builtin_bit_cast(float, u << 16); }
__device__ inline float b2f_hi(unsigned u) { return __builtin_bit_cast(float, u & 0xffff0000u); }
__device__ inline float b2f(unsigned short s) { return __builtin_bit_cast(float, ((unsigned)s) << 16); }

// ---------------- CSR build ----------------

__global__ void count_k(const int* __restrict__ dst, int* __restrict__ cnt) {
  int e = blockIdx.x * blockDim.x + threadIdx.x;
  if (e < NE) atomicAdd(&cnt[dst[e]], 1);
}

// pass 1: per-block sums of 1024 counts (98 blocks x 256 thr, int4 loads)
__global__ __launch_bounds__(256) void bsum_k(const int* __restrict__ cnt,
                                              int* __restrict__ bsum) {
  __shared__ int s[256];
  int t = threadIdx.x;
  int4 c = *(const int4*)(cnt + (size_t)blockIdx.x * 1024 + t * 4);
  s[t] = c.x + c.y + c.z + c.w;
  __syncthreads();
  #pragma unroll
  for (int d = 128; d > 0; d >>= 1) {
    if (t < d) s[t] += s[t + d];
    __syncthreads();
  }
  if (t == 0) bsum[blockIdx.x] = s[0];
}

// pass 2: exclusive scan of 98 block sums (in place), one tiny block
__global__ __launch_bounds__(128) void bscan_k(int* __restrict__ bsum) {
  __shared__ int s[128];
  int t = threadIdx.x;
  int v = (t < 98) ? bsum[t] : 0;
  s[t] = v;
  __syncthreads();
  #pragma unroll
  for (int d = 1; d < 128; d <<= 1) {
    int u = (t >= d) ? s[t - d] : 0;
    __syncthreads();
    s[t] += u;
    __syncthreads();
  }
  bsum[t] = s[t] - v;   // exclusive
}

// pass 3: block-wide scan + block prefix -> offsets (int4 writes)
__global__ __launch_bounds__(256) void off_k(const int* __restrict__ cnt,
                                             const int* __restrict__ bsum,
                                             int* __restrict__ off) {
  __shared__ int s[256];
  int t = threadIdx.x;
  int4 c = *(const int4*)(cnt + (size_t)blockIdx.x * 1024 + t * 4);
  int ts = c.x + c.y + c.z + c.w;
  s[t] = ts;
  __syncthreads();
  #pragma unroll
  for (int d = 1; d < 256; d <<= 1) {
    int u = (t >= d) ? s[t - d] : 0;
    __syncthreads();
    s[t] += u;
    __syncthreads();
  }
  int base = bsum[blockIdx.x] + s[t] - ts;
  int4 o;
  o.x = base;
  o.y = base + c.x;
  o.z = o.y + c.y;
  o.w = o.z + c.z;
  *(int4*)(off + (size_t)blockIdx.x * 1024 + t * 4) = o;
}

__global__ void fill_k(const int* __restrict__ src, const int* __restrict__ dst,
                       const int* __restrict__ off, int* __restrict__ cur,
                       int* __restrict__ csr) {
  int e = blockIdx.x * blockDim.x + threadIdx.x;
  if (e >= NE) return;
  int d = dst[e];
  int p = atomicAdd(&cur[d], 1);
  csr[off[d] + p] = src[e];
}

// ---------------- pack weights into 32x32x16 MFMA B-fragment order ---------
// Bpack[nf][kk][lane][j]: n = nf*32 + (lane&31);
//   j=0..3 -> k = kk*16 +     (lane>>5)*4 + j
//   j=4..7 -> k = kk*16 + 8 + (lane>>5)*4 + (j-4)

__global__ void prep_b_k(const float* __restrict__ w1l, const float* __restrict__ w1r,
                         const float* __restrict__ w2l, const float* __restrict__ w2r,
                         unsigned short* __restrict__ b1p, unsigned short* __restrict__ b2p) {
  int e = blockIdx.x * blockDim.x + threadIdx.x;
  if (e >= 6144) return;
  bool g2 = e >= 4096;
  int le = g2 ? e - 4096 : e;
  int nf = le >> 9, kk = (le >> 6) & 7, l = le & 63;
  int n = nf * 32 + (l & 31), half = l >> 5;
  const float* Wlo = g2 ? w2l : w1l;
  const float* Whi = g2 ? w2r : w1r;
  int split = g2 ? 64 : 128;
  unsigned short o[8];
  #pragma unroll
  for (int j = 0; j < 8; ++j) {
    int k = kk * 16 + ((j >= 4) ? 8 : 0) + half * 4 + (j & 3);
    float v = (n < split) ? Wlo[(size_t)n * 128 + k] : Whi[(size_t)(n - split) * 128 + k];
    o[j] = f2b(v);
  }
  unsigned short* dstp = (g2 ? b2p : b1p) + (size_t)le * 8;
  *(short8*)dstp = __builtin_bit_cast(short8, *(const ulonglong2*)o);
}

// ---------------- MFMA GEMM: C[m,n] = sum_k A[m,k]*W[n,k], K=128 ----------

template<int NCOLS, bool AFP32>
__global__ __launch_bounds__(512, 2) void gemm_k(const void* __restrict__ Aptr, int M,
                                                 const unsigned short* __restrict__ Bpack,
                                                 unsigned short* __restrict__ C) {
  constexpr int NF = NCOLS / 64;          // n-frags per wave
  __shared__ unsigned short As[128 * 128];
  const int t  = threadIdx.x;
  const int m0 = blockIdx.x * 128;

  #pragma unroll
  for (int i = 0; i < 4; ++i) {
    int G = t + 512 * i;
    int r = G >> 4, g = G & 15;
    int m = m0 + r;
    short8 v = {0, 0, 0, 0, 0, 0, 0, 0};
    if (AFP32) {
      if (m < M) {
        const float* p = (const float*)Aptr + (size_t)m * 128 + g * 8;
        float4 a = *(const float4*)p;
        float4 b = *(const float4*)(p + 4);
        v[0] = (short)f2b(a.x); v[1] = (short)f2b(a.y);
        v[2] = (short)f2b(a.z); v[3] = (short)f2b(a.w);
        v[4] = (short)f2b(b.x); v[5] = (short)f2b(b.y);
        v[6] = (short)f2b(b.z); v[7] = (short)f2b(b.w);
      }
    } else {
      if (m < M) v = *(const short8*)((const unsigned short*)Aptr + (size_t)m * 128 + g * 8);
    }
    *(short8*)(As + r * 128 + ((g ^ (r & 15)) << 3)) = v;
  }
  __syncthreads();

  const int wid = t >> 6, lane = t & 63;
  const int mw = wid >> 1, nw = wid & 1;
  const int m = mw * 32 + (lane & 31), half = lane >> 5;

  short8 af[8];
  #pragma unroll
  for (int kk = 0; kk < 8; ++kk) {
    const unsigned* p0 = (const unsigned*)(As + m * 128 + (((2 * kk)     ^ (m & 15)) << 3) + half * 4);
    const unsigned* p1 = (const unsigned*)(As + m * 128 + (((2 * kk + 1) ^ (m & 15)) << 3) + half * 4);
    uint4 comb = make_uint4(p0[0], p0[1], p1[0], p1[1]);
    af[kk] = __builtin_bit_cast(short8, comb);
  }

  #pragma unroll
  for (int nf = 0; nf < NF; ++nf) {
    const int nfg = nw * NF + nf;
    f32x16 acc;
    #pragma unroll
    for (int i = 0; i < 16; ++i) acc[i] = 0.f;
    #pragma unroll
    for (int kk = 0; kk < 8; ++kk) {
      short8 bf = *(const short8*)(Bpack + ((size_t)((nfg * 8 + kk) * 64 + lane)) * 8);
      acc = __builtin_amdgcn_mfma_f32_32x32x16_bf16(af[kk], bf, acc, 0, 0, 0);
    }
    const int col = nfg * 32 + (lane & 31);
    #pragma unroll
    for (int q = 0; q < 4; ++q)
      #pragma unroll
      for (int rr = 0; rr < 4; ++rr) {
        int row = rr + 8 * q + 4 * half;
        int mo  = m0 + mw * 32 + row;
        if (mo < M) C[(size_t)mo * NCOLS + col] = f2b(acc[q * 4 + rr]);
      }
  }
}

// ---------------- layer-1 aggregate + bias + self + relu (bf16 in/out) -----

__global__ __launch_bounds__(256) void agg1_k(const unsigned short* __restrict__ xlr,
                                              const int* __restrict__ off,
                                              const int* __restrict__ csr,
                                              const float* __restrict__ b1,
                                              unsigned short* __restrict__ h) {
  int wid  = (blockIdx.x * blockDim.x + threadIdx.x) >> 6;
  int lane = threadIdx.x & 63;
  if (wid >= NN) return;
  int s0 = off[wid], s1 = off[wid + 1];
  float ax = 0.f, ay = 0.f;
  int e = s0;
  for (; e + 3 < s1; e += 4) {
    int j0 = csr[e], j1 = csr[e + 1], j2 = csr[e + 2], j3 = csr[e + 3];
    unsigned u0 = *(const unsigned*)(xlr + (size_t)j0 * 256 + 2 * lane);
    unsigned u1 = *(const unsigned*)(xlr + (size_t)j1 * 256 + 2 * lane);
    unsigned u2 = *(const unsigned*)(xlr + (size_t)j2 * 256 + 2 * lane);
    unsigned u3 = *(const unsigned*)(xlr + (size_t)j3 * 256 + 2 * lane);
    ax += (b2f_lo(u0) + b2f_lo(u1)) + (b2f_lo(u2) + b2f_lo(u3));
    ay += (b2f_hi(u0) + b2f_hi(u1)) + (b2f_hi(u2) + b2f_hi(u3));
  }
  for (; e < s1; ++e) {
    unsigned u = *(const unsigned*)(xlr + (size_t)csr[e] * 256 + 2 * lane);
    ax += b2f_lo(u); ay += b2f_hi(u);
  }
  float inv = 1.f / fmaxf((float)(s1 - s0), 1.f);
  unsigned su = *(const unsigned*)(xlr + (size_t)wid * 256 + 128 + 2 * lane);
  float2 bb = *(const float2*)(b1 + 2 * lane);
  float h0 = fmaxf(fmaf(ax, inv, bb.x + b2f_lo(su)), 0.f);
  float h1 = fmaxf(fmaf(ay, inv, bb.y + b2f_hi(su)), 0.f);
  unsigned packed = (unsigned)f2b(h0) | ((unsigned)f2b(h1) << 16);
  *(unsigned*)(h + (size_t)wid * 128 + 2 * lane) = packed;
}

// ---------------- layer-2 aggregate + bias + self -> out (fp32) ------------

__global__ __launch_bounds__(256) void agg2_k(const unsigned short* __restrict__ hlr,
                                              const int* __restrict__ off,
                                              const int* __restrict__ csr,
                                              const float* __restrict__ b2,
                                              float* __restrict__ out) {
  int wid  = (blockIdx.x * blockDim.x + threadIdx.x) >> 6;
  int lane = threadIdx.x & 63;
  if (wid >= NN) return;
  int s0 = off[wid], s1 = off[wid + 1];
  float a = 0.f;
  int e = s0;
  for (; e + 3 < s1; e += 4) {
    int j0 = csr[e], j1 = csr[e + 1], j2 = csr[e + 2], j3 = csr[e + 3];
    float v0 = b2f(hlr[(size_t)j0 * 128 + lane]);
    float v1 = b2f(hlr[(size_t)j1 * 128 + lane]);
    float v2 = b2f(hlr[(size_t)j2 * 128 + lane]);
    float v3 = b2f(hlr[(size_t)j3 * 128 + lane]);
    a += (v0 + v1) + (v2 + v3);
  }
  for (; e < s1; ++e) a += b2f(hlr[(size_t)csr[e] * 128 + lane]);
  float inv = 1.f / fmaxf((float)(s1 - s0), 1.f);
  float r   = b2f(hlr[(size_t)wid * 128 + 64 + lane]);
  out[(size_t)wid * 64 + lane] = fmaf(a, inv, b2[lane] + r);
}

// ---------------- launch ----------------

extern "C" void kernel_launch(void* const* d_in, const int* in_sizes, int n_in,
                              void* d_out, int out_size, void* d_ws, size_t ws_size,
                              hipStream_t stream) {
  const float* x   = (const float*)d_in[0];
  const int*   ei  = (const int*)d_in[1];
  const float* w1l = (const float*)d_in[2];
  const float* b1  = (const float*)d_in[3];
  const float* w1r = (const float*)d_in[4];
  const float* w2l = (const float*)d_in[5];
  const float* b2  = (const float*)d_in[6];
  const float* w2r = (const float*)d_in[7];
  float* out = (float*)d_out;

  const int* src = ei;
  const int* dst = ei + NE;

  int* cnt  = (int*)d_ws + W_CNT;
  int* cur  = (int*)d_ws + W_CUR;
  int* bsum = (int*)d_ws + W_BSUM;
  int* off  = (int*)d_ws + W_OFF;
  int* csr  = (int*)d_ws + W_CSR;
  unsigned short* b1p = (unsigned short*)((int*)d_ws + W_B1);
  unsigned short* b2p = (unsigned short*)((int*)d_ws + W_B2);
  unsigned short* xlr = (unsigned short*)((int*)d_ws + W_XLR);  // [NN][256]
  unsigned short* h   = (unsigned short*)((int*)d_ws + W_H);    // [NN][128]
  unsigned short* hlr = (unsigned short*)((int*)d_ws + W_HLR);  // [NN][128]

  // zero cnt (incl. pad) + cur
  hipMemsetAsync((int*)d_ws + W_CNT, 0, (W_BSUM - W_CNT) * 4, stream);

  const int eb = (NE + 255) / 256;
  count_k<<<eb, 256, 0, stream>>>(dst, cnt);
  bsum_k<<<98, 256, 0, stream>>>(cnt, bsum);
  bscan_k<<<1, 128, 0, stream>>>(bsum);
  off_k<<<98, 256, 0, stream>>>(cnt, bsum, off);
  fill_k<<<eb, 256, 0, stream>>>(src, dst, off, cur, csr);
  prep_b_k<<<24, 256, 0, stream>>>(w1l, w1r, w2l, w2r, b1p, b2p);

  const int gb = (NN + 127) / 128;   // 782

  // GEMM1: xlr = bf16( x @ [W1l|W1r]^T )  [NN][256]
  gemm_k<256, true><<<gb, 512, 0, stream>>>((const void*)x, NN, b1p, xlr);

  // agg1: h = bf16( relu(mean(xl) + b1 + xr) )  [NN][128]
  agg1_k<<<(NN * 64 + 255) / 256, 256, 0, stream>>>(xlr, off, csr, b1, h);

  // GEMM2: hlr = bf16( h @ [W2l|W2r]^T )  [NN][128]
  gemm_k<128, false><<<gb, 512, 0, stream>>>((const void*)h, NN, b2p, hlr);

  // agg2: out = mean(hl) + b2 + hr  (fp32)
  agg2_k<<<(NN * 64 + 255) / 256, 256, 0, stream>>>(hlr, off, csr, b2, out);
}

// Round 4
// 262.445 us; speedup vs baseline: 3.0777x; 1.3658x over previous
//
#include <hip/hip_runtime.h>

// ---------------------------------------------------------------------------
// GraphSAGE 2-layer (mean aggr), N=100000, E=1600000, 128 -> 128(relu) -> 64
// Project-then-aggregate; bf16 MFMA GEMMs; bf16 intermediate features;
// CSR built via LDS-binned counting sort (NO global fine-grained atomics,
// no write amplification).
// ---------------------------------------------------------------------------

namespace {
constexpr int NN   = 100000;
constexpr int NE   = 1600000;
constexpr int NBKT = 391;            // buckets of 256 nodes: dst >> 8
constexpr int PB   = 256;            // partition blocks
constexpr int CE   = NE / PB;        // 6250 edges per partition block

// workspace layout in 4-byte words (16B-aligned regions)
constexpr size_t W_BKT  = 0;         // int[392]  bucket counts
constexpr size_t W_BASE = 400;       // int[392]  bucket bases (excl scan)
constexpr size_t W_BCUR = 800;       // int[392]  bucket alloc cursors
constexpr size_t W_OFF  = 1200;      // int[100416] CSR row offsets
constexpr size_t W_PART = 101616;    // int[NE]   bucket-sorted packed edges
constexpr size_t W_CSR  = 1701616;   // int[NE]   CSR adjacency (src ids)
constexpr size_t W_B1   = 3301616;   // ushort[8*8*64*8] packed W1 (16384 words)
constexpr size_t W_B2   = 3318000;   // ushort[4*8*64*8] packed W2 (8192 words)
constexpr size_t W_XLR  = 3326192;   // bf16 [NN][256]
constexpr size_t W_H    = 16126192;  // bf16 [NN][128]
constexpr size_t W_HLR  = 22526192;  // bf16 [NN][128]
// end = 28,926,192 words = 115.7 MB
}

using short8  = __attribute__((ext_vector_type(8)))  short;
using f32x16  = __attribute__((ext_vector_type(16))) float;

__device__ inline unsigned short f2b(float f) {   // fp32 -> bf16 RNE
  unsigned u = __builtin_bit_cast(unsigned, f);
  u = (u + 0x7fffu + ((u >> 16) & 1u)) >> 16;
  return (unsigned short)u;
}
__device__ inline float b2f_lo(unsigned u) { return __builtin_bit_cast(float, u << 16); }
__device__ inline float b2f_hi(unsigned u) { return __builtin_bit_cast(float, u & 0xffff0000u); }
__device__ inline float b2f(unsigned short s) { return __builtin_bit_cast(float, ((unsigned)s) << 16); }

// ---------------- CSR build: LDS-binned counting sort ----------------

// pass 0: global bucket counts via per-block LDS histograms
__global__ __launch_bounds__(256) void prebucket_k(const int* __restrict__ dst,
                                                   int* __restrict__ bktCnt) {
  __shared__ int h[NBKT];
  int t = threadIdx.x;
  for (int j = t; j < NBKT; j += 256) h[j] = 0;
  __syncthreads();
  const int base = blockIdx.x * CE;
  for (int i = t; i < CE; i += 256) atomicAdd(&h[dst[base + i] >> 8], 1);
  __syncthreads();
  for (int j = t; j < NBKT; j += 256) if (h[j]) atomicAdd(&bktCnt[j], h[j]);
}

// pass 1: exclusive scan of bucket counts -> bases; init cursors
__global__ __launch_bounds__(512) void scanb_k(const int* __restrict__ bktCnt,
                                               int* __restrict__ bktBase,
                                               int* __restrict__ bktCur) {
  __shared__ int s[512];
  int t = threadIdx.x;
  int v = (t < NBKT) ? bktCnt[t] : 0;
  s[t] = v;
  __syncthreads();
  #pragma unroll
  for (int d = 1; d < 512; d <<= 1) {
    int u = (t >= d) ? s[t - d] : 0;
    __syncthreads();
    s[t] += u;
    __syncthreads();
  }
  int excl = s[t] - v;
  if (t <= NBKT) bktBase[t] = excl;       // bktBase[NBKT] = NE sentinel
  if (t < NBKT)  bktCur[t]  = excl;
}

// pass 2: per-block bucket-sort 6250 edges in LDS, reserve global space,
// write runs out coalesced. part word = ((dst & 255) << 23) | src.
__global__ __launch_bounds__(256) void partition_k(const int* __restrict__ src,
                                                   const int* __restrict__ dst,
                                                   int* __restrict__ bktCur,
                                                   int* __restrict__ part) {
  __shared__ int  hist[NBKT + 1];
  __shared__ int  lo[NBKT + 1];
  __shared__ int  cur[NBKT + 1];
  __shared__ int  gb[NBKT + 1];
  __shared__ int  sh[256];
  __shared__ int  stage[CE];
  __shared__ unsigned short sbkt[CE];
  int t = threadIdx.x;
  const int base = blockIdx.x * CE;

  for (int j = t; j < NBKT + 1; j += 256) hist[j] = 0;
  __syncthreads();
  for (int i = t; i < CE; i += 256) atomicAdd(&hist[dst[base + i] >> 8], 1);
  __syncthreads();

  // exclusive scan of hist[0..NBKT) -> lo; 2 entries per thread (512 padded)
  int j0 = 2 * t, j1 = 2 * t + 1;
  int h0 = (j0 < NBKT) ? hist[j0] : 0;
  int h1 = (j1 < NBKT) ? hist[j1] : 0;
  int ps = h0 + h1;
  sh[t] = ps;
  __syncthreads();
  #pragma unroll
  for (int d = 1; d < 256; d <<= 1) {
    int u = (t >= d) ? sh[t - d] : 0;
    __syncthreads();
    sh[t] += u;
    __syncthreads();
  }
  int e0 = sh[t] - ps;            // exclusive at j0
  if (j0 < NBKT + 1) { lo[j0] = e0; cur[j0] = e0; }
  if (j1 < NBKT + 1) { lo[j1] = e0 + h0; cur[j1] = e0 + h0; }
  __syncthreads();

  // place edges into LDS stage, bucket-sorted
  for (int i = t; i < CE; i += 256) {
    int d = dst[base + i], s = src[base + i];
    int b = d >> 8;
    int p = atomicAdd(&cur[b], 1);
    stage[p] = ((d & 255) << 23) | s;
    sbkt[p]  = (unsigned short)b;
  }
  __syncthreads();

  // reserve contiguous global space per bucket
  for (int j = t; j < NBKT; j += 256)
    gb[j] = hist[j] ? atomicAdd(&bktCur[j], hist[j]) : 0;
  __syncthreads();

  // coalesced write-out (consecutive i -> consecutive global addr per run)
  for (int i = t; i < CE; i += 256) {
    int b = sbkt[i];
    part[gb[b] + (i - lo[b])] = stage[i];
  }
}

// pass 3: per-bucket count + scan + offsets + CSR fill (one block per bucket)
__global__ __launch_bounds__(256) void cfill_k(const int* __restrict__ part,
                                               const int* __restrict__ bktBase,
                                               int* __restrict__ off,
                                               int* __restrict__ csr) {
  __shared__ int cnt[256];
  __shared__ int cur[256];
  __shared__ int sh[256];
  int t = threadIdx.x;
  const int b = blockIdx.x;
  const int beg = bktBase[b], end = bktBase[b + 1];

  cnt[t] = 0;
  __syncthreads();
  for (int i = beg + t; i < end; i += 256)
    atomicAdd(&cnt[((unsigned)part[i]) >> 23], 1);
  __syncthreads();

  int v = cnt[t];
  sh[t] = v;
  __syncthreads();
  #pragma unroll
  for (int d = 1; d < 256; d <<= 1) {
    int u = (t >= d) ? sh[t - d] : 0;
    __syncthreads();
    sh[t] += u;
    __syncthreads();
  }
  int excl = sh[t] - v;
  off[b * 256 + t] = beg + excl;          // covers off[0..100095]; off[NN] falls out
  cur[t] = excl;
  __syncthreads();

  for (int i = beg + t; i < end; i += 256) {
    int w = part[i];
    int j = ((unsigned)w) >> 23;
    int p = atomicAdd(&cur[j], 1);
    csr[beg + p] = w & 0x7FFFFF;
  }
}

// ---------------- pack weights into 32x32x16 MFMA B-fragment order ---------

__global__ void prep_b_k(const float* __restrict__ w1l, const float* __restrict__ w1r,
                         const float* __restrict__ w2l, const float* __restrict__ w2r,
                         unsigned short* __restrict__ b1p, unsigned short* __restrict__ b2p) {
  int e = blockIdx.x * blockDim.x + threadIdx.x;
  if (e >= 6144) return;
  bool g2 = e >= 4096;
  int le = g2 ? e - 4096 : e;
  int nf = le >> 9, kk = (le >> 6) & 7, l = le & 63;
  int n = nf * 32 + (l & 31), half = l >> 5;
  const float* Wlo = g2 ? w2l : w1l;
  const float* Whi = g2 ? w2r : w1r;
  int split = g2 ? 64 : 128;
  unsigned short o[8];
  #pragma unroll
  for (int j = 0; j < 8; ++j) {
    int k = kk * 16 + ((j >= 4) ? 8 : 0) + half * 4 + (j & 3);
    float v = (n < split) ? Wlo[(size_t)n * 128 + k] : Whi[(size_t)(n - split) * 128 + k];
    o[j] = f2b(v);
  }
  unsigned short* dstp = (g2 ? b2p : b1p) + (size_t)le * 8;
  *(short8*)dstp = __builtin_bit_cast(short8, *(const ulonglong2*)o);
}

// ---------------- MFMA GEMM: C[m,n] = sum_k A[m,k]*W[n,k], K=128 ----------

template<int NCOLS, bool AFP32>
__global__ __launch_bounds__(512, 2) void gemm_k(const void* __restrict__ Aptr, int M,
                                                 const unsigned short* __restrict__ Bpack,
                                                 unsigned short* __restrict__ C) {
  constexpr int NF = NCOLS / 64;          // n-frags per wave
  __shared__ unsigned short As[128 * 128];
  const int t  = threadIdx.x;
  const int m0 = blockIdx.x * 128;

  #pragma unroll
  for (int i = 0; i < 4; ++i) {
    int G = t + 512 * i;
    int r = G >> 4, g = G & 15;
    int m = m0 + r;
    short8 v = {0, 0, 0, 0, 0, 0, 0, 0};
    if (AFP32) {
      if (m < M) {
        const float* p = (const float*)Aptr + (size_t)m * 128 + g * 8;
        float4 a = *(const float4*)p;
        float4 b = *(const float4*)(p + 4);
        v[0] = (short)f2b(a.x); v[1] = (short)f2b(a.y);
        v[2] = (short)f2b(a.z); v[3] = (short)f2b(a.w);
        v[4] = (short)f2b(b.x); v[5] = (short)f2b(b.y);
        v[6] = (short)f2b(b.z); v[7] = (short)f2b(b.w);
      }
    } else {
      if (m < M) v = *(const short8*)((const unsigned short*)Aptr + (size_t)m * 128 + g * 8);
    }
    *(short8*)(As + r * 128 + ((g ^ (r & 15)) << 3)) = v;
  }
  __syncthreads();

  const int wid = t >> 6, lane = t & 63;
  const int mw = wid >> 1, nw = wid & 1;
  const int m = mw * 32 + (lane & 31), half = lane >> 5;

  short8 af[8];
  #pragma unroll
  for (int kk = 0; kk < 8; ++kk) {
    const unsigned* p0 = (const unsigned*)(As + m * 128 + (((2 * kk)     ^ (m & 15)) << 3) + half * 4);
    const unsigned* p1 = (const unsigned*)(As + m * 128 + (((2 * kk + 1) ^ (m & 15)) << 3) + half * 4);
    uint4 comb = make_uint4(p0[0], p0[1], p1[0], p1[1]);
    af[kk] = __builtin_bit_cast(short8, comb);
  }

  #pragma unroll
  for (int nf = 0; nf < NF; ++nf) {
    const int nfg = nw * NF + nf;
    f32x16 acc;
    #pragma unroll
    for (int i = 0; i < 16; ++i) acc[i] = 0.f;
    #pragma unroll
    for (int kk = 0; kk < 8; ++kk) {
      short8 bf = *(const short8*)(Bpack + ((size_t)((nfg * 8 + kk) * 64 + lane)) * 8);
      acc = __builtin_amdgcn_mfma_f32_32x32x16_bf16(af[kk], bf, acc, 0, 0, 0);
    }
    const int col = nfg * 32 + (lane & 31);
    #pragma unroll
    for (int q = 0; q < 4; ++q)
      #pragma unroll
      for (int rr = 0; rr < 4; ++rr) {
        int row = rr + 8 * q + 4 * half;
        int mo  = m0 + mw * 32 + row;
        if (mo < M) C[(size_t)mo * NCOLS + col] = f2b(acc[q * 4 + rr]);
      }
  }
}

// ---------------- layer-1 aggregate + bias + self + relu (bf16 in/out) -----

__global__ __launch_bounds__(256) void agg1_k(const unsigned short* __restrict__ xlr,
                                              const int* __restrict__ off,
                                              const int* __restrict__ csr,
                                              const float* __restrict__ b1,
                                              unsigned short* __restrict__ h) {
  int wid  = (blockIdx.x * blockDim.x + threadIdx.x) >> 6;
  int lane = threadIdx.x & 63;
  if (wid >= NN) return;
  int s0 = off[wid], s1 = off[wid + 1];
  float ax = 0.f, ay = 0.f;
  int e = s0;
  for (; e + 3 < s1; e += 4) {
    int j0 = csr[e], j1 = csr[e + 1], j2 = csr[e + 2], j3 = csr[e + 3];
    unsigned u0 = *(const unsigned*)(xlr + (size_t)j0 * 256 + 2 * lane);
    unsigned u1 = *(const unsigned*)(xlr + (size_t)j1 * 256 + 2 * lane);
    unsigned u2 = *(const unsigned*)(xlr + (size_t)j2 * 256 + 2 * lane);
    unsigned u3 = *(const unsigned*)(xlr + (size_t)j3 * 256 + 2 * lane);
    ax += (b2f_lo(u0) + b2f_lo(u1)) + (b2f_lo(u2) + b2f_lo(u3));
    ay += (b2f_hi(u0) + b2f_hi(u1)) + (b2f_hi(u2) + b2f_hi(u3));
  }
  for (; e < s1; ++e) {
    unsigned u = *(const unsigned*)(xlr + (size_t)csr[e] * 256 + 2 * lane);
    ax += b2f_lo(u); ay += b2f_hi(u);
  }
  float inv = 1.f / fmaxf((float)(s1 - s0), 1.f);
  unsigned su = *(const unsigned*)(xlr + (size_t)wid * 256 + 128 + 2 * lane);
  float2 bb = *(const float2*)(b1 + 2 * lane);
  float h0 = fmaxf(fmaf(ax, inv, bb.x + b2f_lo(su)), 0.f);
  float h1 = fmaxf(fmaf(ay, inv, bb.y + b2f_hi(su)), 0.f);
  unsigned packed = (unsigned)f2b(h0) | ((unsigned)f2b(h1) << 16);
  *(unsigned*)(h + (size_t)wid * 128 + 2 * lane) = packed;
}

// ---------------- layer-2 aggregate + bias + self -> out (fp32) ------------

__global__ __launch_bounds__(256) void agg2_k(const unsigned short* __restrict__ hlr,
                                              const int* __restrict__ off,
                                              const int* __restrict__ csr,
                                              const float* __restrict__ b2,
                                              float* __restrict__ out) {
  int wid  = (blockIdx.x * blockDim.x + threadIdx.x) >> 6;
  int lane = threadIdx.x & 63;
  if (wid >= NN) return;
  int s0 = off[wid], s1 = off[wid + 1];
  float a = 0.f;
  int e = s0;
  for (; e + 3 < s1; e += 4) {
    int j0 = csr[e], j1 = csr[e + 1], j2 = csr[e + 2], j3 = csr[e + 3];
    float v0 = b2f(hlr[(size_t)j0 * 128 + lane]);
    float v1 = b2f(hlr[(size_t)j1 * 128 + lane]);
    float v2 = b2f(hlr[(size_t)j2 * 128 + lane]);
    float v3 = b2f(hlr[(size_t)j3 * 128 + lane]);
    a += (v0 + v1) + (v2 + v3);
  }
  for (; e < s1; ++e) a += b2f(hlr[(size_t)csr[e] * 128 + lane]);
  float inv = 1.f / fmaxf((float)(s1 - s0), 1.f);
  float r   = b2f(hlr[(size_t)wid * 128 + 64 + lane]);
  out[(size_t)wid * 64 + lane] = fmaf(a, inv, b2[lane] + r);
}

// ---------------- launch ----------------

extern "C" void kernel_launch(void* const* d_in, const int* in_sizes, int n_in,
                              void* d_out, int out_size, void* d_ws, size_t ws_size,
                              hipStream_t stream) {
  const float* x   = (const float*)d_in[0];
  const int*   ei  = (const int*)d_in[1];
  const float* w1l = (const float*)d_in[2];
  const float* b1  = (const float*)d_in[3];
  const float* w1r = (const float*)d_in[4];
  const float* w2l = (const float*)d_in[5];
  const float* b2  = (const float*)d_in[6];
  const float* w2r = (const float*)d_in[7];
  float* out = (float*)d_out;

  const int* src = ei;
  const int* dst = ei + NE;

  int* bktCnt  = (int*)d_ws + W_BKT;
  int* bktBase = (int*)d_ws + W_BASE;
  int* bktCur  = (int*)d_ws + W_BCUR;
  int* off     = (int*)d_ws + W_OFF;
  int* part    = (int*)d_ws + W_PART;
  int* csr     = (int*)d_ws + W_CSR;
  unsigned short* b1p = (unsigned short*)((int*)d_ws + W_B1);
  unsigned short* b2p = (unsigned short*)((int*)d_ws + W_B2);
  unsigned short* xlr = (unsigned short*)((int*)d_ws + W_XLR);  // [NN][256]
  unsigned short* h   = (unsigned short*)((int*)d_ws + W_H);    // [NN][128]
  unsigned short* hlr = (unsigned short*)((int*)d_ws + W_HLR);  // [NN][128]

  hipMemsetAsync(bktCnt, 0, 400 * 4, stream);

  prebucket_k<<<PB, 256, 0, stream>>>(dst, bktCnt);
  scanb_k<<<1, 512, 0, stream>>>(bktCnt, bktBase, bktCur);
  partition_k<<<PB, 256, 0, stream>>>(src, dst, bktCur, part);
  cfill_k<<<NBKT, 256, 0, stream>>>(part, bktBase, off, csr);
  prep_b_k<<<24, 256, 0, stream>>>(w1l, w1r, w2l, w2r, b1p, b2p);

  const int gb = (NN + 127) / 128;   // 782

  // GEMM1: xlr = bf16( x @ [W1l|W1r]^T )  [NN][256]
  gemm_k<256, true><<<gb, 512, 0, stream>>>((const void*)x, NN, b1p, xlr);

  // agg1: h = bf16( relu(mean(xl) + b1 + xr) )  [NN][128]
  agg1_k<<<(NN * 64 + 255) / 256, 256, 0, stream>>>(xlr, off, csr, b1, h);

  // GEMM2: hlr = bf16( h @ [W2l|W2r]^T )  [NN][128]
  gemm_k<128, false><<<gb, 512, 0, stream>>>((const void*)h, NN, b2p, hlr);

  // agg2: out = mean(hl) + b2 + hr  (fp32)
  agg2_k<<<(NN * 64 + 255) / 256, 256, 0, stream>>>(hlr, off, csr, b2, out);
}

// Round 5
// 258.712 us; speedup vs baseline: 3.1221x; 1.0144x over previous
//
#include <hip/hip_runtime.h>

// ---------------------------------------------------------------------------
// GraphSAGE 2-layer (mean aggr), N=100000, E=1600000, 128 -> 128(relu) -> 64
// Project-then-aggregate; bf16 MFMA GEMMs; layer-1 gathered features (xl)
// stored fp8-e4m3 to halve gather traffic; CSR via LDS-binned counting sort.
// ---------------------------------------------------------------------------

namespace {
constexpr int NN   = 100000;
constexpr int NE   = 1600000;
constexpr int NBKT = 391;            // buckets of 256 nodes: dst >> 8
constexpr int PB   = 256;            // partition blocks
constexpr int CE   = NE / PB;        // 6250 edges per partition block

// workspace layout in 4-byte words (16B-aligned regions)
constexpr size_t W_BKT  = 0;         // int[392]  bucket counts
constexpr size_t W_BASE = 400;       // int[392]  bucket bases (excl scan)
constexpr size_t W_BCUR = 800;       // int[392]  bucket alloc cursors
constexpr size_t W_OFF  = 1200;      // int[100416] CSR row offsets
constexpr size_t W_PART = 101616;    // int[NE]   bucket-sorted packed edges
constexpr size_t W_CSR  = 1701616;   // int[NE]   CSR adjacency (src ids)
constexpr size_t W_B1   = 3301616;   // ushort[8*8*64*8] packed W1
constexpr size_t W_B2   = 3318000;   // ushort[4*8*64*8] packed W2
constexpr size_t W_XQ   = 3326192;   // fp8  [NN][128]  (xl, gathered)
constexpr size_t W_XR   = 6526192;   // bf16 [NN][128]  (xr, self path)
constexpr size_t W_H    = 12926192;  // bf16 [NN][128]
constexpr size_t W_HLR  = 19326192;  // bf16 [NN][128]
// end = 25,726,192 words = 102.9 MB
}

using short8  = __attribute__((ext_vector_type(8)))  short;
using f32x16  = __attribute__((ext_vector_type(16))) float;
using floatx2 = __attribute__((ext_vector_type(2)))  float;

__device__ inline unsigned short f2b(float f) {   // fp32 -> bf16 RNE
  unsigned u = __builtin_bit_cast(unsigned, f);
  u = (u + 0x7fffu + ((u >> 16) & 1u)) >> 16;
  return (unsigned short)u;
}
__device__ inline float b2f_lo(unsigned u) { return __builtin_bit_cast(float, u << 16); }
__device__ inline float b2f_hi(unsigned u) { return __builtin_bit_cast(float, u & 0xffff0000u); }
__device__ inline float b2f(unsigned short s) { return __builtin_bit_cast(float, ((unsigned)s) << 16); }

// ---------------- CSR build: LDS-binned counting sort ----------------

__global__ __launch_bounds__(256) void prebucket_k(const int* __restrict__ dst,
                                                   int* __restrict__ bktCnt) {
  __shared__ int h[NBKT];
  int t = threadIdx.x;
  for (int j = t; j < NBKT; j += 256) h[j] = 0;
  __syncthreads();
  const int base = blockIdx.x * CE;
  for (int i = t; i < CE; i += 256) atomicAdd(&h[dst[base + i] >> 8], 1);
  __syncthreads();
  for (int j = t; j < NBKT; j += 256) if (h[j]) atomicAdd(&bktCnt[j], h[j]);
}

__global__ __launch_bounds__(512) void scanb_k(const int* __restrict__ bktCnt,
                                               int* __restrict__ bktBase,
                                               int* __restrict__ bktCur) {
  __shared__ int s[512];
  int t = threadIdx.x;
  int v = (t < NBKT) ? bktCnt[t] : 0;
  s[t] = v;
  __syncthreads();
  #pragma unroll
  for (int d = 1; d < 512; d <<= 1) {
    int u = (t >= d) ? s[t - d] : 0;
    __syncthreads();
    s[t] += u;
    __syncthreads();
  }
  int excl = s[t] - v;
  if (t <= NBKT) bktBase[t] = excl;       // bktBase[NBKT] = NE sentinel
  if (t < NBKT)  bktCur[t]  = excl;
}

__global__ __launch_bounds__(256) void partition_k(const int* __restrict__ src,
                                                   const int* __restrict__ dst,
                                                   int* __restrict__ bktCur,
                                                   int* __restrict__ part) {
  __shared__ int  hist[NBKT + 1];
  __shared__ int  lo[NBKT + 1];
  __shared__ int  cur[NBKT + 1];
  __shared__ int  gb[NBKT + 1];
  __shared__ int  sh[256];
  __shared__ int  stage[CE];
  __shared__ unsigned short sbkt[CE];
  int t = threadIdx.x;
  const int base = blockIdx.x * CE;

  for (int j = t; j < NBKT + 1; j += 256) hist[j] = 0;
  __syncthreads();
  for (int i = t; i < CE; i += 256) atomicAdd(&hist[dst[base + i] >> 8], 1);
  __syncthreads();

  int j0 = 2 * t, j1 = 2 * t + 1;
  int h0 = (j0 < NBKT) ? hist[j0] : 0;
  int h1 = (j1 < NBKT) ? hist[j1] : 0;
  int ps = h0 + h1;
  sh[t] = ps;
  __syncthreads();
  #pragma unroll
  for (int d = 1; d < 256; d <<= 1) {
    int u = (t >= d) ? sh[t - d] : 0;
    __syncthreads();
    sh[t] += u;
    __syncthreads();
  }
  int e0 = sh[t] - ps;
  if (j0 < NBKT + 1) { lo[j0] = e0; cur[j0] = e0; }
  if (j1 < NBKT + 1) { lo[j1] = e0 + h0; cur[j1] = e0 + h0; }
  __syncthreads();

  for (int i = t; i < CE; i += 256) {
    int d = dst[base + i], s = src[base + i];
    int b = d >> 8;
    int p = atomicAdd(&cur[b], 1);
    stage[p] = ((d & 255) << 23) | s;
    sbkt[p]  = (unsigned short)b;
  }
  __syncthreads();

  for (int j = t; j < NBKT; j += 256)
    gb[j] = hist[j] ? atomicAdd(&bktCur[j], hist[j]) : 0;
  __syncthreads();

  for (int i = t; i < CE; i += 256) {
    int b = sbkt[i];
    part[gb[b] + (i - lo[b])] = stage[i];
  }
}

__global__ __launch_bounds__(256) void cfill_k(const int* __restrict__ part,
                                               const int* __restrict__ bktBase,
                                               int* __restrict__ off,
                                               int* __restrict__ csr) {
  __shared__ int cnt[256];
  __shared__ int cur[256];
  __shared__ int sh[256];
  int t = threadIdx.x;
  const int b = blockIdx.x;
  const int beg = bktBase[b], end = bktBase[b + 1];

  cnt[t] = 0;
  __syncthreads();
  for (int i = beg + t; i < end; i += 256)
    atomicAdd(&cnt[((unsigned)part[i]) >> 23], 1);
  __syncthreads();

  int v = cnt[t];
  sh[t] = v;
  __syncthreads();
  #pragma unroll
  for (int d = 1; d < 256; d <<= 1) {
    int u = (t >= d) ? sh[t - d] : 0;
    __syncthreads();
    sh[t] += u;
    __syncthreads();
  }
  int excl = sh[t] - v;
  off[b * 256 + t] = beg + excl;
  cur[t] = excl;
  __syncthreads();

  for (int i = beg + t; i < end; i += 256) {
    int w = part[i];
    int j = ((unsigned)w) >> 23;
    int p = atomicAdd(&cur[j], 1);
    csr[beg + p] = w & 0x7FFFFF;
  }
}

// ---------------- pack weights into 32x32x16 MFMA B-fragment order ---------

__global__ void prep_b_k(const float* __restrict__ w1l, const float* __restrict__ w1r,
                         const float* __restrict__ w2l, const float* __restrict__ w2r,
                         unsigned short* __restrict__ b1p, unsigned short* __restrict__ b2p) {
  int e = blockIdx.x * blockDim.x + threadIdx.x;
  if (e >= 6144) return;
  bool g2 = e >= 4096;
  int le = g2 ? e - 4096 : e;
  int nf = le >> 9, kk = (le >> 6) & 7, l = le & 63;
  int n = nf * 32 + (l & 31), half = l >> 5;
  const float* Wlo = g2 ? w2l : w1l;
  const float* Whi = g2 ? w2r : w1r;
  int split = g2 ? 64 : 128;
  unsigned short o[8];
  #pragma unroll
  for (int j = 0; j < 8; ++j) {
    int k = kk * 16 + ((j >= 4) ? 8 : 0) + half * 4 + (j & 3);
    float v = (n < split) ? Wlo[(size_t)n * 128 + k] : Whi[(size_t)(n - split) * 128 + k];
    o[j] = f2b(v);
  }
  unsigned short* dstp = (g2 ? b2p : b1p) + (size_t)le * 8;
  *(short8*)dstp = __builtin_bit_cast(short8, *(const ulonglong2*)o);
}

// ---------------- MFMA GEMM: C[m,n] = sum_k A[m,k]*W[n,k], K=128 ----------
// MODE 0: write bf16 to C ([M][NCOLS]).
// MODE 1: cols <128 -> fp8 e4m3 to Q ([M][128]); cols >=128 -> bf16 to C ([M][128]).

template<int NCOLS, bool AFP32, int MODE>
__global__ __launch_bounds__(512, 2) void gemm_k(const void* __restrict__ Aptr, int M,
                                                 const unsigned short* __restrict__ Bpack,
                                                 unsigned short* __restrict__ C,
                                                 unsigned char* __restrict__ Q) {
  constexpr int NF = NCOLS / 64;          // n-frags per wave
  __shared__ unsigned short As[128 * 128];
  const int t  = threadIdx.x;
  const int m0 = blockIdx.x * 128;

  #pragma unroll
  for (int i = 0; i < 4; ++i) {
    int G = t + 512 * i;
    int r = G >> 4, g = G & 15;
    int m = m0 + r;
    short8 v = {0, 0, 0, 0, 0, 0, 0, 0};
    if (AFP32) {
      if (m < M) {
        const float* p = (const float*)Aptr + (size_t)m * 128 + g * 8;
        float4 a = *(const float4*)p;
        float4 b = *(const float4*)(p + 4);
        v[0] = (short)f2b(a.x); v[1] = (short)f2b(a.y);
        v[2] = (short)f2b(a.z); v[3] = (short)f2b(a.w);
        v[4] = (short)f2b(b.x); v[5] = (short)f2b(b.y);
        v[6] = (short)f2b(b.z); v[7] = (short)f2b(b.w);
      }
    } else {
      if (m < M) v = *(const short8*)((const unsigned short*)Aptr + (size_t)m * 128 + g * 8);
    }
    *(short8*)(As + r * 128 + ((g ^ (r & 15)) << 3)) = v;
  }
  __syncthreads();

  const int wid = t >> 6, lane = t & 63;
  const int mw = wid >> 1, nw = wid & 1;
  const int m = mw * 32 + (lane & 31), half = lane >> 5;

  short8 af[8];
  #pragma unroll
  for (int kk = 0; kk < 8; ++kk) {
    const unsigned* p0 = (const unsigned*)(As + m * 128 + (((2 * kk)     ^ (m & 15)) << 3) + half * 4);
    const unsigned* p1 = (const unsigned*)(As + m * 128 + (((2 * kk + 1) ^ (m & 15)) << 3) + half * 4);
    uint4 comb = make_uint4(p0[0], p0[1], p1[0], p1[1]);
    af[kk] = __builtin_bit_cast(short8, comb);
  }

  #pragma unroll
  for (int nf = 0; nf < NF; ++nf) {
    const int nfg = nw * NF + nf;
    f32x16 acc;
    #pragma unroll
    for (int i = 0; i < 16; ++i) acc[i] = 0.f;
    #pragma unroll
    for (int kk = 0; kk < 8; ++kk) {
      short8 bf = *(const short8*)(Bpack + ((size_t)((nfg * 8 + kk) * 64 + lane)) * 8);
      acc = __builtin_amdgcn_mfma_f32_32x32x16_bf16(af[kk], bf, acc, 0, 0, 0);
    }
    const int col = nfg * 32 + (lane & 31);
    #pragma unroll
    for (int q = 0; q < 4; ++q)
      #pragma unroll
      for (int rr = 0; rr < 4; ++rr) {
        int row = rr + 8 * q + 4 * half;
        int mo  = m0 + mw * 32 + row;
        if (mo < M) {
          float v = acc[q * 4 + rr];
          if (MODE == 0) {
            C[(size_t)mo * NCOLS + col] = f2b(v);
          } else {
            if (col < 128) {
              int p8 = __builtin_amdgcn_cvt_pk_fp8_f32(v, v, 0, false);
              Q[(size_t)mo * 128 + col] = (unsigned char)(p8 & 0xff);
            } else {
              C[(size_t)mo * 128 + (col - 128)] = f2b(v);
            }
          }
        }
      }
  }
}

// ---------------- layer-1 aggregate + bias + self + relu -------------------
// gather fp8 xq rows (128 B/edge), self from bf16 xr; write bf16 h.

__global__ __launch_bounds__(256) void agg1_k(const unsigned char* __restrict__ xq,
                                              const unsigned short* __restrict__ xr,
                                              const int* __restrict__ off,
                                              const int* __restrict__ csr,
                                              const float* __restrict__ b1,
                                              unsigned short* __restrict__ h) {
  int wid  = (blockIdx.x * blockDim.x + threadIdx.x) >> 6;
  int lane = threadIdx.x & 63;
  if (wid >= NN) return;
  int s0 = off[wid], s1 = off[wid + 1];
  float ax = 0.f, ay = 0.f;
  int e = s0;
  for (; e + 3 < s1; e += 4) {
    int j0 = csr[e], j1 = csr[e + 1], j2 = csr[e + 2], j3 = csr[e + 3];
    unsigned u0 = *(const unsigned short*)(xq + (size_t)j0 * 128 + 2 * lane);
    unsigned u1 = *(const unsigned short*)(xq + (size_t)j1 * 128 + 2 * lane);
    unsigned u2 = *(const unsigned short*)(xq + (size_t)j2 * 128 + 2 * lane);
    unsigned u3 = *(const unsigned short*)(xq + (size_t)j3 * 128 + 2 * lane);
    floatx2 f0 = __builtin_amdgcn_cvt_pk_f32_fp8(u0, false);
    floatx2 f1 = __builtin_amdgcn_cvt_pk_f32_fp8(u1, false);
    floatx2 f2 = __builtin_amdgcn_cvt_pk_f32_fp8(u2, false);
    floatx2 f3 = __builtin_amdgcn_cvt_pk_f32_fp8(u3, false);
    ax += (f0.x + f1.x) + (f2.x + f3.x);
    ay += (f0.y + f1.y) + (f2.y + f3.y);
  }
  for (; e < s1; ++e) {
    unsigned u = *(const unsigned short*)(xq + (size_t)csr[e] * 128 + 2 * lane);
    floatx2 f = __builtin_amdgcn_cvt_pk_f32_fp8(u, false);
    ax += f.x; ay += f.y;
  }
  float inv = 1.f / fmaxf((float)(s1 - s0), 1.f);
  unsigned su = *(const unsigned*)(xr + (size_t)wid * 128 + 2 * lane);
  float2 bb = *(const float2*)(b1 + 2 * lane);
  float h0 = fmaxf(fmaf(ax, inv, bb.x + b2f_lo(su)), 0.f);
  float h1 = fmaxf(fmaf(ay, inv, bb.y + b2f_hi(su)), 0.f);
  unsigned packed = (unsigned)f2b(h0) | ((unsigned)f2b(h1) << 16);
  *(unsigned*)(h + (size_t)wid * 128 + 2 * lane) = packed;
}

// ---------------- layer-2 aggregate + bias + self -> out (fp32) ------------

__global__ __launch_bounds__(256) void agg2_k(const unsigned short* __restrict__ hlr,
                                              const int* __restrict__ off,
                                              const int* __restrict__ csr,
                                              const float* __restrict__ b2,
                                              float* __restrict__ out) {
  int wid  = (blockIdx.x * blockDim.x + threadIdx.x) >> 6;
  int lane = threadIdx.x & 63;
  if (wid >= NN) return;
  int s0 = off[wid], s1 = off[wid + 1];
  float a = 0.f;
  int e = s0;
  for (; e + 3 < s1; e += 4) {
    int j0 = csr[e], j1 = csr[e + 1], j2 = csr[e + 2], j3 = csr[e + 3];
    float v0 = b2f(hlr[(size_t)j0 * 128 + lane]);
    float v1 = b2f(hlr[(size_t)j1 * 128 + lane]);
    float v2 = b2f(hlr[(size_t)j2 * 128 + lane]);
    float v3 = b2f(hlr[(size_t)j3 * 128 + lane]);
    a += (v0 + v1) + (v2 + v3);
  }
  for (; e < s1; ++e) a += b2f(hlr[(size_t)csr[e] * 128 + lane]);
  float inv = 1.f / fmaxf((float)(s1 - s0), 1.f);
  float r   = b2f(hlr[(size_t)wid * 128 + 64 + lane]);
  out[(size_t)wid * 64 + lane] = fmaf(a, inv, b2[lane] + r);
}

// ---------------- launch ----------------

extern "C" void kernel_launch(void* const* d_in, const int* in_sizes, int n_in,
                              void* d_out, int out_size, void* d_ws, size_t ws_size,
                              hipStream_t stream) {
  const float* x   = (const float*)d_in[0];
  const int*   ei  = (const int*)d_in[1];
  const float* w1l = (const float*)d_in[2];
  const float* b1  = (const float*)d_in[3];
  const float* w1r = (const float*)d_in[4];
  const float* w2l = (const float*)d_in[5];
  const float* b2  = (const float*)d_in[6];
  const float* w2r = (const float*)d_in[7];
  float* out = (float*)d_out;

  const int* src = ei;
  const int* dst = ei + NE;

  int* bktCnt  = (int*)d_ws + W_BKT;
  int* bktBase = (int*)d_ws + W_BASE;
  int* bktCur  = (int*)d_ws + W_BCUR;
  int* off     = (int*)d_ws + W_OFF;
  int* part    = (int*)d_ws + W_PART;
  int* csr     = (int*)d_ws + W_CSR;
  unsigned short* b1p = (unsigned short*)((int*)d_ws + W_B1);
  unsigned short* b2p = (unsigned short*)((int*)d_ws + W_B2);
  unsigned char*  xq  = (unsigned char*)((int*)d_ws + W_XQ);   // fp8 [NN][128]
  unsigned short* xr  = (unsigned short*)((int*)d_ws + W_XR);  // bf16 [NN][128]
  unsigned short* h   = (unsigned short*)((int*)d_ws + W_H);   // bf16 [NN][128]
  unsigned short* hlr = (unsigned short*)((int*)d_ws + W_HLR); // bf16 [NN][128]

  hipMemsetAsync(bktCnt, 0, 400 * 4, stream);

  prebucket_k<<<PB, 256, 0, stream>>>(dst, bktCnt);
  scanb_k<<<1, 512, 0, stream>>>(bktCnt, bktBase, bktCur);
  partition_k<<<PB, 256, 0, stream>>>(src, dst, bktCur, part);
  cfill_k<<<NBKT, 256, 0, stream>>>(part, bktBase, off, csr);
  prep_b_k<<<24, 256, 0, stream>>>(w1l, w1r, w2l, w2r, b1p, b2p);

  const int gb = (NN + 127) / 128;   // 782

  // GEMM1: xq = fp8(x @ W1l^T), xr = bf16(x @ W1r^T)
  gemm_k<256, true, 1><<<gb, 512, 0, stream>>>((const void*)x, NN, b1p, xr, xq);

  // agg1: h = bf16( relu(mean_fp8(xl) + b1 + xr) )
  agg1_k<<<(NN * 64 + 255) / 256, 256, 0, stream>>>(xq, xr, off, csr, b1, h);

  // GEMM2: hlr = bf16( h @ [W2l|W2r]^T )  [NN][128]
  gemm_k<128, false, 0><<<gb, 512, 0, stream>>>((const void*)h, NN, b2p, hlr, nullptr);

  // agg2: out = mean(hl) + b2 + hr  (fp32)
  agg2_k<<<(NN * 64 + 255) / 256, 256, 0, stream>>>(hlr, off, csr, b2, out);
}